// Round 12
// baseline (246.555 us; speedup 1.0000x reference)
//
#include <hip/hip_runtime.h>
#include <math.h>

#define BS   2048
#define SEQ  50
#define NPOS (BS * SEQ)

typedef __attribute__((ext_vector_type(8))) short bf16x8;   // 8 bf16 = 4 VGPR
typedef __attribute__((ext_vector_type(4))) float f32x4;

__device__ __forceinline__ float sigf(float x) { return 1.0f / (1.0f + __expf(-x)); }
__device__ __forceinline__ float tanhfast(float x) {
    float e = __expf(2.0f * x);
    return 1.0f - 2.0f / (e + 1.0f);
}
__device__ __forceinline__ unsigned short bfrn(float x) {   // fp32 -> bf16 rne
    unsigned int u = __float_as_uint(x);
    u += 0x7FFFu + ((u >> 16) & 1u);
    return (unsigned short)(u >> 16);
}
__device__ __forceinline__ float bf2f(unsigned short h) {
    return __uint_as_float(((unsigned int)h) << 16);
}

#define FMA4(A, X, W) \
    A = fmaf((X).x, (W).x, A); A = fmaf((X).y, (W).y, A); \
    A = fmaf((X).z, (W).z, A); A = fmaf((X).w, (W).w, A);

// ---------------------------------------------------------------------------
// Precomputed attention tables (position-independent):
//   Wvf[64][10]: Wv . Wf(:,0:10)
//   Ce [64][9]:  (Wf(:,10+e)+bf) . Wv
//   Ag [4][10][7]: g_h[k] = Ag[h][k][0:6].self6 + Ag[h][k][6]
//   Bd [9][4][7]:  dd[e][h] = Bd[e][h][0:6].self6 + Bd[e][h][6]
// ---------------------------------------------------------------------------
__device__ float Wvf_d[640];
__device__ float Ce_d[576];
__device__ float Ag_d[280];
__device__ float Bd_d[252];

// ---------------------------------------------------------------------------
// prep (unchanged — two-stage Ag/Bd build, fast).
// ---------------------------------------------------------------------------
__global__ __launch_bounds__(512) void prep_all(
    const float* __restrict__ Wih, const float* __restrict__ Whh,
    bf16x8* __restrict__ whF, bf16x8* __restrict__ wiF,
    const float* __restrict__ Wf, const float* __restrict__ bf,
    const float* __restrict__ Wq, const float* __restrict__ bq,
    const float* __restrict__ Wv,
    const float* __restrict__ Wk, const float* __restrict__ bk)
{
    __shared__ float sG[640];   // G[n][k] = Wq[n,:].Wf[:,k]
    __shared__ float sD[576];   // D[e][n]

    if (blockIdx.x < 48) {
        int id = blockIdx.x * 512 + threadIdx.x;
        const float* src;
        bf16x8* dst;
        int p;
        if (id < 16384) {
            int l = id & 63, frag = id >> 6;        // 0..255
            p = frag & 1;
            int kc = (frag >> 1) & 3, ti = (frag >> 3) & 3, w = frag >> 5;
            int n  = (w + 8 * ti) * 16 + (l & 15);
            int k0 = kc * 32 + (l >> 4) * 8;
            src = &Whh[n * 128 + k0];
            dst = &whF[frag * 64 + l];
        } else {
            int id2 = id - 16384;
            int l = id2 & 63, frag = id2 >> 6;      // 0..127
            p = frag & 1;
            int kc = (frag >> 1) & 1, tile = frag >> 2;
            int n  = tile * 16 + (l & 15);
            int k0 = kc * 32 + (l >> 4) * 8;
            src = &Wih[n * 64 + k0];
            dst = &wiF[frag * 64 + l];
        }
        bf16x8 v;
        #pragma unroll
        for (int j = 0; j < 8; ++j) {
            float x = src[j];
            unsigned short hi = bfrn(x);
            unsigned short r  = p ? bfrn(x - bf2f(hi)) : hi;
            v[j] = (short)r;
        }
        *dst = v;
        return;
    }

    if (blockIdx.x < 51) {               // Wvf (640) + Ce (576), flat
        int i = (blockIdx.x - 48) * 512 + threadIdx.x;   // 0..1535
        if (i >= 1216) return;
        if (i < 640) {
            int o = i / 10, k = i % 10;
            float s = 0.f;
            #pragma unroll 8
            for (int j = 0; j < 64; ++j) s = fmaf(Wv[o * 64 + j], Wf[j * 19 + k], s);
            Wvf_d[i] = s;
        } else {
            int i2 = i - 640;
            int o = i2 / 9, e = i2 % 9;
            float s = 0.f;
            #pragma unroll 8
            for (int j = 0; j < 64; ++j)
                s = fmaf(Wf[j * 19 + 10 + e] + bf[j], Wv[o * 64 + j], s);
            Ce_d[i2] = s;
        }
        return;
    }

    // block 51: stage 1 — G and D into LDS
    const int t = threadIdx.x;
    for (int i = t; i < 1216; i += 512) {
        if (i < 640) {
            int n = i / 10, k = i % 10;
            float s = 0.f;
            #pragma unroll 8
            for (int j = 0; j < 64; ++j) s = fmaf(Wq[n * 64 + j], Wf[j * 19 + k], s);
            sG[i] = s;
        } else {
            int i2 = i - 640;
            int e = i2 >> 6, n = i2 & 63;
            float s = bq[n];
            #pragma unroll 8
            for (int j = 0; j < 64; ++j)
                s = fmaf(Wf[j * 19 + 10 + e] + bf[j], Wq[n * 64 + j], s);
            sD[i2] = s;
        }
    }
    __syncthreads();
    // stage 2 — fold with Wk/bk (16 FMA each)
    for (int i = t; i < 532; i += 512) {
        if (i < 280) {                   // Ag: i = (h*10+k)*7 + jj
            int h = i / 70, rem = i % 70, k = rem / 7, jj = rem % 7;
            float s = 0.f;
            #pragma unroll
            for (int d = 0; d < 16; ++d) {
                int n = h * 16 + d;
                float wkj = (jj < 6) ? Wk[n * 6 + jj] : bk[n];
                s = fmaf(wkj, sG[n * 10 + k], s);
            }
            Ag_d[i] = s;
        } else {                         // Bd: i4 = (e*4+h)*7 + jj
            int i4 = i - 280;
            int e = i4 / 28, rem = i4 % 28, h = rem / 7, jj = rem % 7;
            float s = 0.f;
            #pragma unroll
            for (int d = 0; d < 16; ++d) {
                int n = h * 16 + d;
                float wkj = (jj < 6) ? Wk[n * 6 + jj] : bk[n];
                s = fmaf(wkj, sD[e * 64 + n], s);
            }
            Bd_d[i4] = s;
        }
    }
}

// ---------------------------------------------------------------------------
// Kernel A v8: one lane = one position, transaction-shaped.
//  - SINGLE pass over input, held in registers: 27 float2 (seqs, 8B-aligned)
//    + 9 float4 (ets, 16B-aligned) + 9 int loads = 45 strided wave-instrs
//    (v7 issued ~195 scalar ones, each touching 64 L1 lines).
//  - COALESCED output: lane writes its 64 results to LDS so[tid][68]
//    (odd-granule stride -> conflict-free b128), one barrier, block copies
//    LDS->global as 4096 coalesced float4.  DS cost: 32 wave-instrs per 64
//    positions (~0.5/pos vs v4's ~73/pos — wave width now spans positions).
//  - LDS 69.6 KB -> 2 blocks/CU.  Grid 400 x 256 = NPOS exactly.
// ---------------------------------------------------------------------------
__global__ __launch_bounds__(256) void edge_attn_ctx(
    const float* __restrict__ seqs,   // [BS,SEQ,3,3,6]
    const float* __restrict__ ets,    // [BS,SEQ,3,3,4]
    const int*   __restrict__ masks,  // [BS,SEQ,3,3]
    const float* __restrict__ bv,
    float* __restrict__ ctx)          // [BS,SEQ,64]
{
    const int t = threadIdx.x;
    const int p = blockIdx.x * 256 + t;

    __shared__ float so[256 * 68];    // 69632 B, stride 68 (17 granules, odd)

    // ---- input: single pass, vector loads, register-held ----
    float sq[54];
    {
        const float2* s2 = (const float2*)(seqs + (size_t)p * 54);
        #pragma unroll
        for (int i = 0; i < 27; ++i) {
            float2 v = s2[i];
            sq[2*i] = v.x; sq[2*i+1] = v.y;
        }
    }
    float et[36];
    {
        const float4* e4 = (const float4*)(ets + (size_t)p * 36);
        #pragma unroll
        for (int i = 0; i < 9; ++i) {
            float4 v = e4[i];
            et[4*i]=v.x; et[4*i+1]=v.y; et[4*i+2]=v.z; et[4*i+3]=v.w;
        }
    }
    int mk[9];
    {
        const int* mp = masks + (size_t)p * 9;
        #pragma unroll
        for (int e = 0; e < 9; ++e) mk[e] = mp[e];
    }

    const float s0 = sq[24], s1 = sq[25], s2 = sq[26],
                s3 = sq[27], s4 = sq[28], s5 = sq[29];

    // g[h][k] = Ag[h][k] . [self6, 1]
    float g[4][10];
    #pragma unroll
    for (int h = 0; h < 4; ++h)
        #pragma unroll
        for (int k = 0; k < 10; ++k) {
            const float* a = &Ag_d[(h * 10 + k) * 7];
            float v = a[6];
            v = fmaf(s0, a[0], v); v = fmaf(s1, a[1], v);
            v = fmaf(s2, a[2], v); v = fmaf(s3, a[3], v);
            v = fmaf(s4, a[4], v); v = fmaf(s5, a[5], v);
            g[h][k] = v;
        }

    // att[e][h] (pre-softmax) + per-head max — raw10 from registers
    float att[9][4];
    float mx0 = -3.0e38f, mx1 = -3.0e38f, mx2 = -3.0e38f, mx3 = -3.0e38f;
    #pragma unroll
    for (int e = 0; e < 9; ++e) {
        #pragma unroll
        for (int h = 0; h < 4; ++h) {
            const float* b = &Bd_d[(e * 4 + h) * 7];
            float a = b[6];
            a = fmaf(s0, b[0], a); a = fmaf(s1, b[1], a);
            a = fmaf(s2, b[2], a); a = fmaf(s3, b[3], a);
            a = fmaf(s4, b[4], a); a = fmaf(s5, b[5], a);
            a = fmaf(sq[e*6+0], g[h][0], a); a = fmaf(sq[e*6+1], g[h][1], a);
            a = fmaf(sq[e*6+2], g[h][2], a); a = fmaf(sq[e*6+3], g[h][3], a);
            a = fmaf(sq[e*6+4], g[h][4], a); a = fmaf(sq[e*6+5], g[h][5], a);
            a = fmaf(et[e*4+0], g[h][6], a); a = fmaf(et[e*4+1], g[h][7], a);
            a = fmaf(et[e*4+2], g[h][8], a); a = fmaf(et[e*4+3], g[h][9], a);
            a *= 0.25f;
            a = (mk[e] == 0) ? -1.0e10f : a;
            att[e][h] = a;
            if (h == 0) mx0 = fmaxf(mx0, a);
            if (h == 1) mx1 = fmaxf(mx1, a);
            if (h == 2) mx2 = fmaxf(mx2, a);
            if (h == 3) mx3 = fmaxf(mx3, a);
        }
    }

    // exp + per-head sums
    float ss0 = 0.f, ss1 = 0.f, ss2 = 0.f, ss3 = 0.f;
    #pragma unroll
    for (int e = 0; e < 9; ++e) {
        att[e][0] = __expf(att[e][0] - mx0); ss0 += att[e][0];
        att[e][1] = __expf(att[e][1] - mx1); ss1 += att[e][1];
        att[e][2] = __expf(att[e][2] - mx2); ss2 += att[e][2];
        att[e][3] = __expf(att[e][3] - mx3); ss3 += att[e][3];
    }

    // rb[h][k] = sum_e att[e][h]*raw10_e[k]  (raw10 still in registers)
    float rb[4][10];
    #pragma unroll
    for (int h = 0; h < 4; ++h)
        #pragma unroll
        for (int k = 0; k < 10; ++k) rb[h][k] = 0.f;
    #pragma unroll
    for (int e = 0; e < 9; ++e) {
        #pragma unroll
        for (int h = 0; h < 4; ++h) {
            const float w = att[e][h];
            rb[h][0] = fmaf(w, sq[e*6+0], rb[h][0]);
            rb[h][1] = fmaf(w, sq[e*6+1], rb[h][1]);
            rb[h][2] = fmaf(w, sq[e*6+2], rb[h][2]);
            rb[h][3] = fmaf(w, sq[e*6+3], rb[h][3]);
            rb[h][4] = fmaf(w, sq[e*6+4], rb[h][4]);
            rb[h][5] = fmaf(w, sq[e*6+5], rb[h][5]);
            rb[h][6] = fmaf(w, et[e*4+0], rb[h][6]);
            rb[h][7] = fmaf(w, et[e*4+1], rb[h][7]);
            rb[h][8] = fmaf(w, et[e*4+2], rb[h][8]);
            rb[h][9] = fmaf(w, et[e*4+3], rb[h][9]);
        }
    }
    const float iv0 = 1.f / ss0, iv1 = 1.f / ss1, iv2 = 1.f / ss2, iv3 = 1.f / ss3;

    // ctx -> LDS (b128, conflict-free via odd granule stride)
    #pragma unroll
    for (int o4 = 0; o4 < 16; ++o4) {
        float r0_, r1_, r2_, r3_;
        #pragma unroll
        for (int j = 0; j < 4; ++j) {
            const int o = o4 * 4 + j;
            const int h = o >> 4;
            const float inv = (h == 0) ? iv0 : (h == 1) ? iv1 : (h == 2) ? iv2 : iv3;
            const float* wv = &Wvf_d[o * 10];
            const float* ce = &Ce_d[o * 9];
            float acc = 0.f;
            #pragma unroll
            for (int k = 0; k < 10; ++k) acc = fmaf(rb[h][k], wv[k], acc);
            #pragma unroll
            for (int e = 0; e < 9; ++e) acc = fmaf(att[e][h], ce[e], acc);
            acc = acc * inv + bv[o];
            if (j == 0) r0_ = acc;
            if (j == 1) r1_ = acc;
            if (j == 2) r2_ = acc;
            if (j == 3) r3_ = acc;
        }
        *(float4*)&so[t * 68 + o4 * 4] = make_float4(r0_, r1_, r2_, r3_);
    }
    __syncthreads();

    // coalesced copy LDS -> global (4096 float4 per block)
    {
        float4* cg = (float4*)(ctx + (size_t)blockIdx.x * 256 * 64);
        #pragma unroll
        for (int it = 0; it < 16; ++it) {
            int c = t + 256 * it;
            int pos = c >> 4, wi = c & 15;
            cg[c] = *(const float4*)&so[pos * 68 + wi * 4];
        }
    }
}

// ---------------------------------------------------------------------------
// Kernel C v13: pair-step MFMA LSTM, all weights in registers (unchanged;
// ~110 us).
// ---------------------------------------------------------------------------
#define MFMA16(A, B, C) __builtin_amdgcn_mfma_f32_16x16x32_bf16(A, B, C, 0, 0, 0)
#define MM4(F, W0, W1, W2, W3) \
    a0 = MFMA16(F, W0, a0); a1 = MFMA16(F, W1, a1); \
    a2 = MFMA16(F, W2, a2); a3 = MFMA16(F, W3, a3);

#define HPASS \
    MM4(hfh[0], whr[0][0][0], whr[1][0][0], whr[2][0][0], whr[3][0][0]) \
    MM4(hfh[1], whr[0][1][0], whr[1][1][0], whr[2][1][0], whr[3][1][0]) \
    MM4(hfh[2], whr[0][2][0], whr[1][2][0], whr[2][2][0], whr[3][2][0]) \
    MM4(hfh[3], whr[0][3][0], whr[1][3][0], whr[2][3][0], whr[3][3][0]) \
    MM4(hfl[0], whr[0][0][0], whr[1][0][0], whr[2][0][0], whr[3][0][0]) \
    MM4(hfl[1], whr[0][1][0], whr[1][1][0], whr[2][1][0], whr[3][1][0]) \
    MM4(hfl[2], whr[0][2][0], whr[1][2][0], whr[2][2][0], whr[3][2][0]) \
    MM4(hfl[3], whr[0][3][0], whr[1][3][0], whr[2][3][0], whr[3][3][0]) \
    MM4(hfh[0], whr[0][0][1], whr[1][0][1], whr[2][0][1], whr[3][0][1]) \
    MM4(hfh[1], whr[0][1][1], whr[1][1][1], whr[2][1][1], whr[3][1][1]) \
    MM4(hfh[2], whr[0][2][1], whr[1][2][1], whr[2][2][1], whr[3][2][1]) \
    MM4(hfh[3], whr[0][3][1], whr[1][3][1], whr[2][3][1], whr[3][3][1])

#define REDIST_E(ch, g0, g1) { \
    float s2_ = __shfl_xor(ch[2], 32), s3_ = __shfl_xor(ch[3], 32); \
    g0 = lolq ? ch[0] : s2_;  g1 = lolq ? ch[1] : s3_; }
#define REDIST_O(ch, g0, g1) { \
    float s0_ = __shfl_xor(ch[0], 32), s1_ = __shfl_xor(ch[1], 32); \
    g0 = lolq ? s0_ : ch[2];  g1 = lolq ? s1_ : ch[3]; }

#define PWBODY(gi0,gf0,gg0,go0,gi1,gf1,gg1,go1, WB0, WB1) { \
    float i0_ = sigf(gi0 + bi), f0_ = sigf(gf0 + bff); \
    float gA_ = tanhfast(gg0 + bg), o0_ = sigf(go0 + bo); \
    c20 = fmaf(f0_, c20, i0_ * gA_); \
    float hv0_ = o0_ * tanhfast(c20); \
    float i1_ = sigf(gi1 + bi), f1_ = sigf(gf1 + bff); \
    float gB_ = tanhfast(gg1 + bg), o1_ = sigf(go1 + bo); \
    c21 = fmaf(f1_, c21, i1_ * gB_); \
    float hv1_ = o1_ * tanhfast(c21); \
    unsigned short hh0_ = bfrn(hv0_), hh1_ = bfrn(hv1_); \
    unsigned short hl0_ = bfrn(hv0_ - bf2f(hh0_)), hl1_ = bfrn(hv1_ - bf2f(hh1_)); \
    *(unsigned short*)((char*)s_hh + (WB0)) = hh0_; \
    *(unsigned short*)((char*)s_hl + (WB0)) = hl0_; \
    *(unsigned short*)((char*)s_hh + (WB1)) = hh1_; \
    *(unsigned short*)((char*)s_hl + (WB1)) = hl1_; }

__global__ __launch_bounds__(512, 2) void lstm_mfma(
    const float*  __restrict__ ctx,    // [BS,SEQ,64]
    const bf16x8* __restrict__ whF,    // 16384 frags
    const bf16x8* __restrict__ wiFg,   // 8192 frags
    const float*  __restrict__ b_ih, const float* __restrict__ b_hh,
    const float*  __restrict__ W_out, const float* __restrict__ b_out,
    float* __restrict__ out)           // [BS,64]
{
    const int t  = threadIdx.x;
    const int w  = t >> 6, l = t & 63;
    const int lm = l & 15, lq = l >> 4;
    const int row0 = blockIdx.x * 8;            // 8 real rows per block

    __shared__ unsigned short s_xh[1024], s_xl[1024];   // [16][64] pair tile
    __shared__ unsigned short s_hh[4096], s_hl[4096];   // planes L(0B) H(4096B)

    for (int i = t; i < 1024; i += 512) { s_xh[i] = 0; s_xl[i] = 0; }
    for (int i = t; i < 4096; i += 512) { s_hh[i] = 0; s_hl[i] = 0; }

    // W_hh fragments (hi+lo) -> registers (128 VGPR)
    bf16x8 whr[4][4][2];
    #pragma unroll
    for (int ti = 0; ti < 4; ++ti)
        #pragma unroll
        for (int kc = 0; kc < 4; ++kc)
            #pragma unroll
            for (int p = 0; p < 2; ++p)
                whr[ti][kc][p] = whF[(((w * 4 + ti) * 4 + kc) * 2 + p) * 64 + l];

    // W_ih fragments (hi+lo) -> registers (64 VGPR); wave reads only its own
    bf16x8 wir[2][4][2];
    #pragma unroll
    for (int kc = 0; kc < 2; ++kc)
        #pragma unroll
        for (int ti = 0; ti < 4; ++ti)
            #pragma unroll
            for (int p = 0; p < 2; ++p)
                wir[kc][ti][p] = wiFg[(((w + 8 * ti) * 2 + kc) * 2 + p) * 64 + l];

    const int m = w * 16 + lm;
    const float bi  = b_ih[m]       + b_hh[m];
    const float bff = b_ih[128 + m] + b_hh[128 + m];
    const float bg  = b_ih[256 + m] + b_hh[256 + m];
    const float bo  = b_ih[384 + m] + b_hh[384 + m];

    const int  urb  = ((lq & 1) << 2) | (lq & 2);
    const bool lolq = (lq < 2);
    float c20 = 0.f, c21 = 0.f;

    const int xrow  = t >> 5;
    const int xl32  = t & 31;
    const int srow  = xrow & 7;
    const int spair = xrow >> 3;
    const float2* ctx2 = (const float2*)ctx;
    const int xbase = (row0 + srow) * SEQ + spair;
    const int xwb   = xrow * 128 + ((4 * xl32) ^ ((xrow & 7) << 4));
    const int swzr  = (lm & 7) << 4;
    const int hwb_m = 32 * w + 2 * lm;
    const int wb0e = 4096 + (8 + urb) * 256 + (hwb_m ^ (urb << 4));
    const int wb1e = 4096 + (9 + urb) * 256 + (hwb_m ^ ((urb + 1) << 4));
    const int wb0o = urb * 256 + (hwb_m ^ (urb << 4));
    const int wb1o = (urb + 1) * 256 + (hwb_m ^ ((urb + 1) << 4));

    float2 xv = ctx2[xbase * 32 + xl32];

    for (int u = 0; u < SEQ / 2; ++u) {
        {   // stage x-pair (rows 0-7 = x(s0), rows 8-15 = x(s1))
            unsigned short xh0 = bfrn(xv.x), xh1 = bfrn(xv.y);
            unsigned short xl0 = bfrn(xv.x - bf2f(xh0)), xl1 = bfrn(xv.y - bf2f(xh1));
            *(unsigned int*)((char*)s_xh + xwb) = (unsigned int)xh0 | ((unsigned int)xh1 << 16);
            *(unsigned int*)((char*)s_xl + xwb) = (unsigned int)xl0 | ((unsigned int)xl1 << 16);
        }
        __syncthreads();   // x-pair + h(s0-1) (plane L) visible

        float2 xvn = make_float2(0.f, 0.f);
        if (u + 1 < SEQ / 2) xvn = ctx2[(xbase + 2 * u + 2) * 32 + xl32];

        bf16x8 hfh[4], hfl[4];
        if (u > 0) {
            #pragma unroll
            for (int kc = 0; kc < 4; ++kc) {
                int b = lm * 256 + ((kc * 64 + lq * 16) ^ swzr);   // plane L
                hfh[kc] = *(const bf16x8*)((const char*)s_hh + b);
                hfl[kc] = *(const bf16x8*)((const char*)s_hl + b);
            }
        }
        bf16x8 xfh[2], xfl[2];
        #pragma unroll
        for (int kc = 0; kc < 2; ++kc) {
            int b = lm * 128 + ((kc * 64 + lq * 16) ^ swzr);
            xfh[kc] = *(const bf16x8*)((const char*)s_xh + b);
            xfl[kc] = *(const bf16x8*)((const char*)s_xl + b);
        }

        f32x4 a0 = {0.f,0.f,0.f,0.f}, a1 = a0, a2 = a0, a3 = a0;

        if (u > 0) { HPASS }           // h(s0-1)W -> acc rows 0-7 only

        #pragma unroll                  // x-pass: register weights
        for (int kc = 0; kc < 2; ++kc) {
            MM4(xfh[kc], wir[kc][0][0], wir[kc][1][0], wir[kc][2][0], wir[kc][3][0])
            MM4(xfl[kc], wir[kc][0][0], wir[kc][1][0], wir[kc][2][0], wir[kc][3][0])
            MM4(xfh[kc], wir[kc][0][1], wir[kc][1][1], wir[kc][2][1], wir[kc][3][1])
        }

        {   // even pointwise: rows 0-7
            float gi0, gi1, gf0, gf1, gg0, gg1, go0, go1;
            REDIST_E(a0, gi0, gi1)
            REDIST_E(a1, gf0, gf1)
            REDIST_E(a2, gg0, gg1)
            REDIST_E(a3, go0, go1)
            PWBODY(gi0, gf0, gg0, go0, gi1, gf1, gg1, go1, wb0e, wb1e)
        }

        // ================= ODD step s1 = 2u+1 =================
        __syncthreads();   // h(s0) (plane H) visible
        #pragma unroll
        for (int kc = 0; kc < 4; ++kc) {
            int b = 4096 + lm * 256 + ((kc * 64 + lq * 16) ^ swzr);  // plane H
            hfh[kc] = *(const bf16x8*)((const char*)s_hh + b);
            hfl[kc] = *(const bf16x8*)((const char*)s_hl + b);
        }
        HPASS                          // h(s0)W -> acc rows 8-15 only

        {   // odd pointwise: rows 8-15
            float gi0, gi1, gf0, gf1, gg0, gg1, go0, go1;
            REDIST_O(a0, gi0, gi1)
            REDIST_O(a1, gf0, gf1)
            REDIST_O(a2, gg0, gg1)
            REDIST_O(a3, go0, go1)
            PWBODY(gi0, gf0, gg0, go0, gi1, gf1, gg1, go1, wb0o, wb1o)
        }
        xv = xvn;
    }
    __syncthreads();

    // ---- epilogue: h(SEQ-1)=h(49) is odd -> plane L rows 0-7 ----
    {
        const int row = t >> 5;
        if (row < 8) {
            const int j0 = t & 31, j1 = (t & 31) + 32;
            const int rswz = (row & 7) << 4;
            float accA = b_out[j0], accB = b_out[j1];
            #pragma unroll
            for (int kq = 0; kq < 16; ++kq) {
                int b = row * 256 + ((kq * 16) ^ rswz);
                bf16x8 hh8 = *(const bf16x8*)((const char*)s_hh + b);
                bf16x8 hl8 = *(const bf16x8*)((const char*)s_hl + b);
                #pragma unroll
                for (int e = 0; e < 8; ++e) {
                    float h = bf2f((unsigned short)hh8[e]) + bf2f((unsigned short)hl8[e]);
                    int k = kq * 8 + e;
                    accA = fmaf(h, W_out[j0 * 128 + k], accA);
                    accB = fmaf(h, W_out[j1 * 128 + k], accB);
                }
            }
            out[(row0 + row) * 64 + j0] = accA;
            out[(row0 + row) * 64 + j1] = accB;
        }
    }
}

// ---------------------------------------------------------------------------
extern "C" void kernel_launch(void* const* d_in, const int* in_sizes, int n_in,
                              void* d_out, int out_size, void* d_ws, size_t ws_size,
                              hipStream_t stream) {
    (void)in_sizes; (void)n_in; (void)out_size; (void)ws_size;
    const float* seqs  = (const float*)d_in[0];
    const float* ets   = (const float*)d_in[1];
    const int*   masks = (const int*)d_in[2];
    const float* Wf  = (const float*)d_in[3];
    const float* bf  = (const float*)d_in[4];
    const float* Wk  = (const float*)d_in[5];
    const float* bk  = (const float*)d_in[6];
    const float* Wq  = (const float*)d_in[7];
    const float* bq  = (const float*)d_in[8];
    const float* Wv  = (const float*)d_in[9];
    const float* bv  = (const float*)d_in[10];
    const float* Wih = (const float*)d_in[11];
    const float* Whh = (const float*)d_in[12];
    const float* bih = (const float*)d_in[13];
    const float* bhh = (const float*)d_in[14];
    const float* Wo  = (const float*)d_in[15];
    const float* bo  = (const float*)d_in[16];

    // ws layout: whF 256K | wiF 128K | ctx 26.2M  (attn tables in device globals)
    char* ws = (char*)d_ws;
    bf16x8* whF = (bf16x8*)(ws);
    bf16x8* wiF = (bf16x8*)(ws + 262144);
    float*  ctx = (float*) (ws + 262144 + 131072);

    hipLaunchKernelGGL(prep_all, dim3(52), dim3(512), 0, stream,
                       Wih, Whh, whF, wiF, Wf, bf, Wq, bq, Wv, Wk, bk);
    hipLaunchKernelGGL(edge_attn_ctx, dim3(400), dim3(256), 0, stream,
                       seqs, ets, masks, bv, ctx);
    hipLaunchKernelGGL(lstm_mfma, dim3(256), dim3(512), 0, stream,
                       ctx, whF, wiF, bih, bhh, Wo, bo, (float*)d_out);
}

// Round 13
// 234.849 us; speedup vs baseline: 1.0498x; 1.0498x over previous
//
#include <hip/hip_runtime.h>
#include <math.h>

#define BS   2048
#define SEQ  50
#define NPOS (BS * SEQ)

typedef __attribute__((ext_vector_type(8))) short bf16x8;   // 8 bf16 = 4 VGPR
typedef __attribute__((ext_vector_type(4))) float f32x4;

__device__ __forceinline__ float sigf(float x) { return 1.0f / (1.0f + __expf(-x)); }
__device__ __forceinline__ float tanhfast(float x) {
    float e = __expf(2.0f * x);
    return 1.0f - 2.0f / (e + 1.0f);
}
__device__ __forceinline__ unsigned short bfrn(float x) {   // fp32 -> bf16 rne
    unsigned int u = __float_as_uint(x);
    u += 0x7FFFu + ((u >> 16) & 1u);
    return (unsigned short)(u >> 16);
}
__device__ __forceinline__ float bf2f(unsigned short h) {
    return __uint_as_float(((unsigned int)h) << 16);
}

#define FMA4(A, X, W) \
    A = fmaf((X).x, (W).x, A); A = fmaf((X).y, (W).y, A); \
    A = fmaf((X).z, (W).z, A); A = fmaf((X).w, (W).w, A);

// ---------------------------------------------------------------------------
// Precomputed attention tables (position-independent):
//   Wvf[64][10]: Wv . Wf(:,0:10)
//   Ce [64][9]:  (Wf(:,10+e)+bf) . Wv
//   Ag [4][10][7]: g_h[k] = Ag[h][k][0:6].self6 + Ag[h][k][6]
//   Bd [9][4][7]:  dd[e][h] = Bd[e][h][0:6].self6 + Bd[e][h][6]
// ---------------------------------------------------------------------------
__device__ float Wvf_d[640];
__device__ float Ce_d[576];
__device__ float Ag_d[280];
__device__ float Bd_d[252];

// ---------------------------------------------------------------------------
// prep (unchanged — two-stage Ag/Bd build, fast).
// ---------------------------------------------------------------------------
__global__ __launch_bounds__(512) void prep_all(
    const float* __restrict__ Wih, const float* __restrict__ Whh,
    bf16x8* __restrict__ whF, bf16x8* __restrict__ wiF,
    const float* __restrict__ Wf, const float* __restrict__ bf,
    const float* __restrict__ Wq, const float* __restrict__ bq,
    const float* __restrict__ Wv,
    const float* __restrict__ Wk, const float* __restrict__ bk)
{
    __shared__ float sG[640];   // G[n][k] = Wq[n,:].Wf[:,k]
    __shared__ float sD[576];   // D[e][n]

    if (blockIdx.x < 48) {
        int id = blockIdx.x * 512 + threadIdx.x;
        const float* src;
        bf16x8* dst;
        int p;
        if (id < 16384) {
            int l = id & 63, frag = id >> 6;        // 0..255
            p = frag & 1;
            int kc = (frag >> 1) & 3, ti = (frag >> 3) & 3, w = frag >> 5;
            int n  = (w + 8 * ti) * 16 + (l & 15);
            int k0 = kc * 32 + (l >> 4) * 8;
            src = &Whh[n * 128 + k0];
            dst = &whF[frag * 64 + l];
        } else {
            int id2 = id - 16384;
            int l = id2 & 63, frag = id2 >> 6;      // 0..127
            p = frag & 1;
            int kc = (frag >> 1) & 1, tile = frag >> 2;
            int n  = tile * 16 + (l & 15);
            int k0 = kc * 32 + (l >> 4) * 8;
            src = &Wih[n * 64 + k0];
            dst = &wiF[frag * 64 + l];
        }
        bf16x8 v;
        #pragma unroll
        for (int j = 0; j < 8; ++j) {
            float x = src[j];
            unsigned short hi = bfrn(x);
            unsigned short r  = p ? bfrn(x - bf2f(hi)) : hi;
            v[j] = (short)r;
        }
        *dst = v;
        return;
    }

    if (blockIdx.x < 51) {               // Wvf (640) + Ce (576), flat
        int i = (blockIdx.x - 48) * 512 + threadIdx.x;   // 0..1535
        if (i >= 1216) return;
        if (i < 640) {
            int o = i / 10, k = i % 10;
            float s = 0.f;
            #pragma unroll 8
            for (int j = 0; j < 64; ++j) s = fmaf(Wv[o * 64 + j], Wf[j * 19 + k], s);
            Wvf_d[i] = s;
        } else {
            int i2 = i - 640;
            int o = i2 / 9, e = i2 % 9;
            float s = 0.f;
            #pragma unroll 8
            for (int j = 0; j < 64; ++j)
                s = fmaf(Wf[j * 19 + 10 + e] + bf[j], Wv[o * 64 + j], s);
            Ce_d[i2] = s;
        }
        return;
    }

    // block 51: stage 1 — G and D into LDS
    const int t = threadIdx.x;
    for (int i = t; i < 1216; i += 512) {
        if (i < 640) {
            int n = i / 10, k = i % 10;
            float s = 0.f;
            #pragma unroll 8
            for (int j = 0; j < 64; ++j) s = fmaf(Wq[n * 64 + j], Wf[j * 19 + k], s);
            sG[i] = s;
        } else {
            int i2 = i - 640;
            int e = i2 >> 6, n = i2 & 63;
            float s = bq[n];
            #pragma unroll 8
            for (int j = 0; j < 64; ++j)
                s = fmaf(Wf[j * 19 + 10 + e] + bf[j], Wq[n * 64 + j], s);
            sD[i2] = s;
        }
    }
    __syncthreads();
    // stage 2 — fold with Wk/bk (16 FMA each)
    for (int i = t; i < 532; i += 512) {
        if (i < 280) {                   // Ag: i = (h*10+k)*7 + jj
            int h = i / 70, rem = i % 70, k = rem / 7, jj = rem % 7;
            float s = 0.f;
            #pragma unroll
            for (int d = 0; d < 16; ++d) {
                int n = h * 16 + d;
                float wkj = (jj < 6) ? Wk[n * 6 + jj] : bk[n];
                s = fmaf(wkj, sG[n * 10 + k], s);
            }
            Ag_d[i] = s;
        } else {                         // Bd: i4 = (e*4+h)*7 + jj
            int i4 = i - 280;
            int e = i4 / 28, rem = i4 % 28, h = rem / 7, jj = rem % 7;
            float s = 0.f;
            #pragma unroll
            for (int d = 0; d < 16; ++d) {
                int n = h * 16 + d;
                float wkj = (jj < 6) ? Wk[n * 6 + jj] : bk[n];
                s = fmaf(wkj, sD[e * 64 + n], s);
            }
            Bd_d[i4] = s;
        }
    }
}

// ---------------------------------------------------------------------------
// Kernel A v9: (position, head) parallel — wave = one head x 64 positions.
//  - Heads are independent end-to-end (ctx[p, h*16+i] uses only head h), so
//    splitting by head multiplies wave count x4 (6400 waves vs 1600) while
//    keeping ALL table loads SCALAR (h is wave-uniform via readfirstlane).
//  - Online-softmax rb accumulation: raw10 is loaded ONCE per edge and never
//    retained — per-lane live state drops ~200+ floats (v7/v8, spill zone)
//    to ~60.  Branchless rescale of (m, s, rb[10]) per edge.
//  - Zero LDS, zero barriers, zero shuffles.  Grid 1600 x 256.
// ---------------------------------------------------------------------------
__global__ __launch_bounds__(256) void edge_attn_ctx(
    const float* __restrict__ seqs,   // [BS,SEQ,3,3,6]
    const float* __restrict__ ets,    // [BS,SEQ,3,3,4]
    const int*   __restrict__ masks,  // [BS,SEQ,3,3]
    const float* __restrict__ bv,
    float* __restrict__ ctx)          // [BS,SEQ,64]
{
    const int lane = threadIdx.x & 63;
    const int hu   = __builtin_amdgcn_readfirstlane(threadIdx.x >> 6); // head, SGPR
    const int p    = blockIdx.x * 64 + lane;

    const float* sp = seqs  + (size_t)p * 54;
    const float* ep = ets   + (size_t)p * 36;
    const int*   mp = masks + (size_t)p * 9;

    // self6 (three 8B loads)
    float2 sA = *(const float2*)(sp + 24);
    float2 sB = *(const float2*)(sp + 26);
    float2 sC = *(const float2*)(sp + 28);
    const float s0 = sA.x, s1 = sA.y, s2 = sB.x,
                s3 = sB.y, s4 = sC.x, s5 = sC.y;

    // g[k] for this head (tables scalar: hu is SGPR)
    float g[10];
    #pragma unroll
    for (int k = 0; k < 10; ++k) {
        const float* a = &Ag_d[(hu * 10 + k) * 7];
        float v = a[6];
        v = fmaf(s0, a[0], v); v = fmaf(s1, a[1], v);
        v = fmaf(s2, a[2], v); v = fmaf(s3, a[3], v);
        v = fmaf(s4, a[4], v); v = fmaf(s5, a[5], v);
        g[k] = v;
    }

    // online pass over 9 edges: att[e] (pre-softmax) + running (m, s, rb[10])
    float att[9], rb[10];
    #pragma unroll
    for (int k = 0; k < 10; ++k) rb[k] = 0.f;
    float m = -3.0e38f, s = 0.f;
    #pragma unroll
    for (int e = 0; e < 9; ++e) {
        float2 r01 = *(const float2*)(sp + e * 6);
        float2 r23 = *(const float2*)(sp + e * 6 + 2);
        float2 r45 = *(const float2*)(sp + e * 6 + 4);
        float4 r69 = *(const float4*)(ep + e * 4);
        const int mk = mp[e];

        const float* b = &Bd_d[(e * 4 + hu) * 7];
        float a = b[6];
        a = fmaf(s0, b[0], a); a = fmaf(s1, b[1], a);
        a = fmaf(s2, b[2], a); a = fmaf(s3, b[3], a);
        a = fmaf(s4, b[4], a); a = fmaf(s5, b[5], a);
        a = fmaf(r01.x, g[0], a); a = fmaf(r01.y, g[1], a);
        a = fmaf(r23.x, g[2], a); a = fmaf(r23.y, g[3], a);
        a = fmaf(r45.x, g[4], a); a = fmaf(r45.y, g[5], a);
        a = fmaf(r69.x, g[6], a); a = fmaf(r69.y, g[7], a);
        a = fmaf(r69.z, g[8], a); a = fmaf(r69.w, g[9], a);
        a *= 0.25f;
        a = (mk == 0) ? -1.0e10f : a;
        att[e] = a;

        float nm = fmaxf(m, a);
        float sc = __expf(m - nm);     // 1 if no new max; 0 on first edge
        float w  = __expf(a - nm);
        s = fmaf(s, sc, w);
        rb[0] = fmaf(rb[0], sc, w * r01.x);
        rb[1] = fmaf(rb[1], sc, w * r01.y);
        rb[2] = fmaf(rb[2], sc, w * r23.x);
        rb[3] = fmaf(rb[3], sc, w * r23.y);
        rb[4] = fmaf(rb[4], sc, w * r45.x);
        rb[5] = fmaf(rb[5], sc, w * r45.y);
        rb[6] = fmaf(rb[6], sc, w * r69.x);
        rb[7] = fmaf(rb[7], sc, w * r69.y);
        rb[8] = fmaf(rb[8], sc, w * r69.z);
        rb[9] = fmaf(rb[9], sc, w * r69.w);
        m = nm;
    }

    const float inv = 1.f / s;
    float we[9];
    #pragma unroll
    for (int e = 0; e < 9; ++e) we[e] = __expf(att[e] - m) * inv;
    float rbn[10];
    #pragma unroll
    for (int k = 0; k < 10; ++k) rbn[k] = rb[k] * inv;

    // 16 outputs of this head; 4 coalesced-ish float4 stores
    float4* cp = (float4*)(ctx + (size_t)p * 64 + hu * 16);
    #pragma unroll
    for (int i4 = 0; i4 < 4; ++i4) {
        float r0_, r1_, r2_, r3_;
        #pragma unroll
        for (int j = 0; j < 4; ++j) {
            const int o = hu * 16 + i4 * 4 + j;       // SGPR index
            const float* wv = &Wvf_d[o * 10];
            const float* ce = &Ce_d[o * 9];
            float acc = bv[o];
            #pragma unroll
            for (int k = 0; k < 10; ++k) acc = fmaf(rbn[k], wv[k], acc);
            #pragma unroll
            for (int e = 0; e < 9; ++e) acc = fmaf(we[e], ce[e], acc);
            if (j == 0) r0_ = acc;
            if (j == 1) r1_ = acc;
            if (j == 2) r2_ = acc;
            if (j == 3) r3_ = acc;
        }
        cp[i4] = make_float4(r0_, r1_, r2_, r3_);
    }
}

// ---------------------------------------------------------------------------
// Kernel C v13: pair-step MFMA LSTM, all weights in registers (unchanged;
// ~110 us).
// ---------------------------------------------------------------------------
#define MFMA16(A, B, C) __builtin_amdgcn_mfma_f32_16x16x32_bf16(A, B, C, 0, 0, 0)
#define MM4(F, W0, W1, W2, W3) \
    a0 = MFMA16(F, W0, a0); a1 = MFMA16(F, W1, a1); \
    a2 = MFMA16(F, W2, a2); a3 = MFMA16(F, W3, a3);

#define HPASS \
    MM4(hfh[0], whr[0][0][0], whr[1][0][0], whr[2][0][0], whr[3][0][0]) \
    MM4(hfh[1], whr[0][1][0], whr[1][1][0], whr[2][1][0], whr[3][1][0]) \
    MM4(hfh[2], whr[0][2][0], whr[1][2][0], whr[2][2][0], whr[3][2][0]) \
    MM4(hfh[3], whr[0][3][0], whr[1][3][0], whr[2][3][0], whr[3][3][0]) \
    MM4(hfl[0], whr[0][0][0], whr[1][0][0], whr[2][0][0], whr[3][0][0]) \
    MM4(hfl[1], whr[0][1][0], whr[1][1][0], whr[2][1][0], whr[3][1][0]) \
    MM4(hfl[2], whr[0][2][0], whr[1][2][0], whr[2][2][0], whr[3][2][0]) \
    MM4(hfl[3], whr[0][3][0], whr[1][3][0], whr[2][3][0], whr[3][3][0]) \
    MM4(hfh[0], whr[0][0][1], whr[1][0][1], whr[2][0][1], whr[3][0][1]) \
    MM4(hfh[1], whr[0][1][1], whr[1][1][1], whr[2][1][1], whr[3][1][1]) \
    MM4(hfh[2], whr[0][2][1], whr[1][2][1], whr[2][2][1], whr[3][2][1]) \
    MM4(hfh[3], whr[0][3][1], whr[1][3][1], whr[2][3][1], whr[3][3][1])

#define REDIST_E(ch, g0, g1) { \
    float s2_ = __shfl_xor(ch[2], 32), s3_ = __shfl_xor(ch[3], 32); \
    g0 = lolq ? ch[0] : s2_;  g1 = lolq ? ch[1] : s3_; }
#define REDIST_O(ch, g0, g1) { \
    float s0_ = __shfl_xor(ch[0], 32), s1_ = __shfl_xor(ch[1], 32); \
    g0 = lolq ? s0_ : ch[2];  g1 = lolq ? s1_ : ch[3]; }

#define PWBODY(gi0,gf0,gg0,go0,gi1,gf1,gg1,go1, WB0, WB1) { \
    float i0_ = sigf(gi0 + bi), f0_ = sigf(gf0 + bff); \
    float gA_ = tanhfast(gg0 + bg), o0_ = sigf(go0 + bo); \
    c20 = fmaf(f0_, c20, i0_ * gA_); \
    float hv0_ = o0_ * tanhfast(c20); \
    float i1_ = sigf(gi1 + bi), f1_ = sigf(gf1 + bff); \
    float gB_ = tanhfast(gg1 + bg), o1_ = sigf(go1 + bo); \
    c21 = fmaf(f1_, c21, i1_ * gB_); \
    float hv1_ = o1_ * tanhfast(c21); \
    unsigned short hh0_ = bfrn(hv0_), hh1_ = bfrn(hv1_); \
    unsigned short hl0_ = bfrn(hv0_ - bf2f(hh0_)), hl1_ = bfrn(hv1_ - bf2f(hh1_)); \
    *(unsigned short*)((char*)s_hh + (WB0)) = hh0_; \
    *(unsigned short*)((char*)s_hl + (WB0)) = hl0_; \
    *(unsigned short*)((char*)s_hh + (WB1)) = hh1_; \
    *(unsigned short*)((char*)s_hl + (WB1)) = hl1_; }

__global__ __launch_bounds__(512, 2) void lstm_mfma(
    const float*  __restrict__ ctx,    // [BS,SEQ,64]
    const bf16x8* __restrict__ whF,    // 16384 frags
    const bf16x8* __restrict__ wiFg,   // 8192 frags
    const float*  __restrict__ b_ih, const float* __restrict__ b_hh,
    const float*  __restrict__ W_out, const float* __restrict__ b_out,
    float* __restrict__ out)           // [BS,64]
{
    const int t  = threadIdx.x;
    const int w  = t >> 6, l = t & 63;
    const int lm = l & 15, lq = l >> 4;
    const int row0 = blockIdx.x * 8;            // 8 real rows per block

    __shared__ unsigned short s_xh[1024], s_xl[1024];   // [16][64] pair tile
    __shared__ unsigned short s_hh[4096], s_hl[4096];   // planes L(0B) H(4096B)

    for (int i = t; i < 1024; i += 512) { s_xh[i] = 0; s_xl[i] = 0; }
    for (int i = t; i < 4096; i += 512) { s_hh[i] = 0; s_hl[i] = 0; }

    // W_hh fragments (hi+lo) -> registers (128 VGPR)
    bf16x8 whr[4][4][2];
    #pragma unroll
    for (int ti = 0; ti < 4; ++ti)
        #pragma unroll
        for (int kc = 0; kc < 4; ++kc)
            #pragma unroll
            for (int p = 0; p < 2; ++p)
                whr[ti][kc][p] = whF[(((w * 4 + ti) * 4 + kc) * 2 + p) * 64 + l];

    // W_ih fragments (hi+lo) -> registers (64 VGPR); wave reads only its own
    bf16x8 wir[2][4][2];
    #pragma unroll
    for (int kc = 0; kc < 2; ++kc)
        #pragma unroll
        for (int ti = 0; ti < 4; ++ti)
            #pragma unroll
            for (int p = 0; p < 2; ++p)
                wir[kc][ti][p] = wiFg[(((w + 8 * ti) * 2 + kc) * 2 + p) * 64 + l];

    const int m = w * 16 + lm;
    const float bi  = b_ih[m]       + b_hh[m];
    const float bff = b_ih[128 + m] + b_hh[128 + m];
    const float bg  = b_ih[256 + m] + b_hh[256 + m];
    const float bo  = b_ih[384 + m] + b_hh[384 + m];

    const int  urb  = ((lq & 1) << 2) | (lq & 2);
    const bool lolq = (lq < 2);
    float c20 = 0.f, c21 = 0.f;

    const int xrow  = t >> 5;
    const int xl32  = t & 31;
    const int srow  = xrow & 7;
    const int spair = xrow >> 3;
    const float2* ctx2 = (const float2*)ctx;
    const int xbase = (row0 + srow) * SEQ + spair;
    const int xwb   = xrow * 128 + ((4 * xl32) ^ ((xrow & 7) << 4));
    const int swzr  = (lm & 7) << 4;
    const int hwb_m = 32 * w + 2 * lm;
    const int wb0e = 4096 + (8 + urb) * 256 + (hwb_m ^ (urb << 4));
    const int wb1e = 4096 + (9 + urb) * 256 + (hwb_m ^ ((urb + 1) << 4));
    const int wb0o = urb * 256 + (hwb_m ^ (urb << 4));
    const int wb1o = (urb + 1) * 256 + (hwb_m ^ ((urb + 1) << 4));

    float2 xv = ctx2[xbase * 32 + xl32];

    for (int u = 0; u < SEQ / 2; ++u) {
        {   // stage x-pair (rows 0-7 = x(s0), rows 8-15 = x(s1))
            unsigned short xh0 = bfrn(xv.x), xh1 = bfrn(xv.y);
            unsigned short xl0 = bfrn(xv.x - bf2f(xh0)), xl1 = bfrn(xv.y - bf2f(xh1));
            *(unsigned int*)((char*)s_xh + xwb) = (unsigned int)xh0 | ((unsigned int)xh1 << 16);
            *(unsigned int*)((char*)s_xl + xwb) = (unsigned int)xl0 | ((unsigned int)xl1 << 16);
        }
        __syncthreads();   // x-pair + h(s0-1) (plane L) visible

        float2 xvn = make_float2(0.f, 0.f);
        if (u + 1 < SEQ / 2) xvn = ctx2[(xbase + 2 * u + 2) * 32 + xl32];

        bf16x8 hfh[4], hfl[4];
        if (u > 0) {
            #pragma unroll
            for (int kc = 0; kc < 4; ++kc) {
                int b = lm * 256 + ((kc * 64 + lq * 16) ^ swzr);   // plane L
                hfh[kc] = *(const bf16x8*)((const char*)s_hh + b);
                hfl[kc] = *(const bf16x8*)((const char*)s_hl + b);
            }
        }
        bf16x8 xfh[2], xfl[2];
        #pragma unroll
        for (int kc = 0; kc < 2; ++kc) {
            int b = lm * 128 + ((kc * 64 + lq * 16) ^ swzr);
            xfh[kc] = *(const bf16x8*)((const char*)s_xh + b);
            xfl[kc] = *(const bf16x8*)((const char*)s_xl + b);
        }

        f32x4 a0 = {0.f,0.f,0.f,0.f}, a1 = a0, a2 = a0, a3 = a0;

        if (u > 0) { HPASS }           // h(s0-1)W -> acc rows 0-7 only

        #pragma unroll                  // x-pass: register weights
        for (int kc = 0; kc < 2; ++kc) {
            MM4(xfh[kc], wir[kc][0][0], wir[kc][1][0], wir[kc][2][0], wir[kc][3][0])
            MM4(xfl[kc], wir[kc][0][0], wir[kc][1][0], wir[kc][2][0], wir[kc][3][0])
            MM4(xfh[kc], wir[kc][0][1], wir[kc][1][1], wir[kc][2][1], wir[kc][3][1])
        }

        {   // even pointwise: rows 0-7
            float gi0, gi1, gf0, gf1, gg0, gg1, go0, go1;
            REDIST_E(a0, gi0, gi1)
            REDIST_E(a1, gf0, gf1)
            REDIST_E(a2, gg0, gg1)
            REDIST_E(a3, go0, go1)
            PWBODY(gi0, gf0, gg0, go0, gi1, gf1, gg1, go1, wb0e, wb1e)
        }

        // ================= ODD step s1 = 2u+1 =================
        __syncthreads();   // h(s0) (plane H) visible
        #pragma unroll
        for (int kc = 0; kc < 4; ++kc) {
            int b = 4096 + lm * 256 + ((kc * 64 + lq * 16) ^ swzr);  // plane H
            hfh[kc] = *(const bf16x8*)((const char*)s_hh + b);
            hfl[kc] = *(const bf16x8*)((const char*)s_hl + b);
        }
        HPASS                          // h(s0)W -> acc rows 8-15 only

        {   // odd pointwise: rows 8-15
            float gi0, gi1, gf0, gf1, gg0, gg1, go0, go1;
            REDIST_O(a0, gi0, gi1)
            REDIST_O(a1, gf0, gf1)
            REDIST_O(a2, gg0, gg1)
            REDIST_O(a3, go0, go1)
            PWBODY(gi0, gf0, gg0, go0, gi1, gf1, gg1, go1, wb0o, wb1o)
        }
        xv = xvn;
    }
    __syncthreads();

    // ---- epilogue: h(SEQ-1)=h(49) is odd -> plane L rows 0-7 ----
    {
        const int row = t >> 5;
        if (row < 8) {
            const int j0 = t & 31, j1 = (t & 31) + 32;
            const int rswz = (row & 7) << 4;
            float accA = b_out[j0], accB = b_out[j1];
            #pragma unroll
            for (int kq = 0; kq < 16; ++kq) {
                int b = row * 256 + ((kq * 16) ^ rswz);
                bf16x8 hh8 = *(const bf16x8*)((const char*)s_hh + b);
                bf16x8 hl8 = *(const bf16x8*)((const char*)s_hl + b);
                #pragma unroll
                for (int e = 0; e < 8; ++e) {
                    float h = bf2f((unsigned short)hh8[e]) + bf2f((unsigned short)hl8[e]);
                    int k = kq * 8 + e;
                    accA = fmaf(h, W_out[j0 * 128 + k], accA);
                    accB = fmaf(h, W_out[j1 * 128 + k], accB);
                }
            }
            out[(row0 + row) * 64 + j0] = accA;
            out[(row0 + row) * 64 + j1] = accB;
        }
    }
}

// ---------------------------------------------------------------------------
extern "C" void kernel_launch(void* const* d_in, const int* in_sizes, int n_in,
                              void* d_out, int out_size, void* d_ws, size_t ws_size,
                              hipStream_t stream) {
    (void)in_sizes; (void)n_in; (void)out_size; (void)ws_size;
    const float* seqs  = (const float*)d_in[0];
    const float* ets   = (const float*)d_in[1];
    const int*   masks = (const int*)d_in[2];
    const float* Wf  = (const float*)d_in[3];
    const float* bf  = (const float*)d_in[4];
    const float* Wk  = (const float*)d_in[5];
    const float* bk  = (const float*)d_in[6];
    const float* Wq  = (const float*)d_in[7];
    const float* bq  = (const float*)d_in[8];
    const float* Wv  = (const float*)d_in[9];
    const float* bv  = (const float*)d_in[10];
    const float* Wih = (const float*)d_in[11];
    const float* Whh = (const float*)d_in[12];
    const float* bih = (const float*)d_in[13];
    const float* bhh = (const float*)d_in[14];
    const float* Wo  = (const float*)d_in[15];
    const float* bo  = (const float*)d_in[16];

    // ws layout: whF 256K | wiF 128K | ctx 26.2M  (attn tables in device globals)
    char* ws = (char*)d_ws;
    bf16x8* whF = (bf16x8*)(ws);
    bf16x8* wiF = (bf16x8*)(ws + 262144);
    float*  ctx = (float*) (ws + 262144 + 131072);

    hipLaunchKernelGGL(prep_all, dim3(52), dim3(512), 0, stream,
                       Wih, Whh, whF, wiF, Wf, bf, Wq, bq, Wv, Wk, bk);
    hipLaunchKernelGGL(edge_attn_ctx, dim3(1600), dim3(256), 0, stream,
                       seqs, ets, masks, bv, ctx);
    hipLaunchKernelGGL(lstm_mfma, dim3(256), dim3(512), 0, stream,
                       ctx, whF, wiF, bih, bhh, Wo, bo, (float*)d_out);
}